// Round 5
// baseline (401.736 us; speedup 1.0000x reference)
//
#include <hip/hip_runtime.h>

#define DEVFN __device__ __forceinline__

constexpr int B  = 16;
constexpr int C  = 256;
constexpr int N  = 64 * 64;     // 4096
constexpr int O1 = C + 4;       // 260

typedef __attribute__((ext_vector_type(8)))  short bf16x8;
typedef __attribute__((ext_vector_type(4)))  short bf16x4;
typedef __attribute__((ext_vector_type(16))) float f32x16;
typedef unsigned short ushort_t;

DEVFN short f2bf(float f){
  union { float f; unsigned u; } p; p.f = f;
  unsigned r = p.u + 0x7fffu + ((p.u >> 16) & 1u);   // RNE
  return (short)(r >> 16);
}
DEVFN float lo2f(unsigned u){ union{unsigned u; float f;} p; p.u = u << 16; return p.f; }
DEVFN float hi2f(unsigned u){ union{unsigned u; float f;} p; p.u = u & 0xffff0000u; return p.f; }
DEVFN float bf2f(ushort_t s){ union{unsigned u; float f;} p; p.u = (unsigned)s << 16; return p.f; }

// tanh-form gelu with raw v_rcp: max err ~5e-4 (approx form) + ~1e-6 (rcp)
DEVFN float gelu_fast(float x){
  float y = 1.5957691216f * fmaf(0.044715f * x * x, x, x);
  float s = __builtin_amdgcn_rcpf(1.0f + __expf(-y));
  return x * s;
}

// ---------------- K1: conv1x1 as bf16 MFMA GEMM (ctx out in bf16) ----------
__global__ __launch_bounds__(256, 4)
void k_conv1_mfma(const float* __restrict__ x, const float* __restrict__ w,
                  const float* __restrict__ bias, ushort_t* __restrict__ ctxb,
                  float* __restrict__ gates){
  __shared__ __align__(16) short wlds[16 * 64 * 8];   // 16KB: [kg][m][8]
  __shared__ __align__(16) short xlds[16 * 64 * 8];   // 16KB: [kg][n][8]
  const int tid  = threadIdx.x;
  const int wv   = tid >> 6;
  const int lane = tid & 63;
  const int l31  = lane & 31;
  const int lhi  = lane >> 5;
  const int oBase = blockIdx.y * 64;
  const int pg0   = blockIdx.x * 64;
  const int b  = pg0 >> 12;
  const int n0 = pg0 & 4095;
  const int mw = (wv >> 1) * 32;
  const int nw = (wv & 1) * 32;

  f32x16 acc;
  #pragma unroll
  for(int r = 0; r < 16; r++) acc[r] = 0.f;

  const int rstage = tid & 63;
  const int kg0    = (tid >> 6) * 4;

  for(int kc = 0; kc < 256; kc += 128){
    __syncthreads();
    {
      const int o = oBase + rstage;
      const float* wp = w + o * 256 + kc;
      #pragma unroll
      for(int t = 0; t < 4; t++){
        const int kg = kg0 + t;
        bf16x8 v;
        if(o < O1){
          const float4 f0 = *(const float4*)(wp + kg * 8);
          const float4 f1 = *(const float4*)(wp + kg * 8 + 4);
          v[0] = f2bf(f0.x); v[1] = f2bf(f0.y); v[2] = f2bf(f0.z); v[3] = f2bf(f0.w);
          v[4] = f2bf(f1.x); v[5] = f2bf(f1.y); v[6] = f2bf(f1.z); v[7] = f2bf(f1.w);
        } else {
          #pragma unroll
          for(int j = 0; j < 8; j++) v[j] = 0;
        }
        *(bf16x8*)&wlds[(kg * 64 + rstage) * 8] = v;
      }
    }
    {
      const float* xp = x + (size_t)b * C * N + (size_t)kc * N + n0 + rstage;
      #pragma unroll
      for(int t = 0; t < 4; t++){
        const int kg = kg0 + t;
        float f[8];
        #pragma unroll
        for(int j = 0; j < 8; j++) f[j] = xp[(size_t)(kg * 8 + j) * N];
        bf16x8 v;
        #pragma unroll
        for(int j = 0; j < 8; j++) v[j] = f2bf(f[j]);
        *(bf16x8*)&xlds[(kg * 64 + rstage) * 8] = v;
      }
    }
    __syncthreads();
    #pragma unroll
    for(int ks = 0; ks < 8; ks++){
      const int kg = ks * 2 + lhi;
      bf16x8 af = *(const bf16x8*)&wlds[(kg * 64 + mw + l31) * 8];
      bf16x8 bfr = *(const bf16x8*)&xlds[(kg * 64 + nw + l31) * 8];
      acc = __builtin_amdgcn_mfma_f32_32x32x16_bf16(af, bfr, acc, 0, 0, 0);
    }
  }

  const int n = n0 + nw + l31;
  #pragma unroll
  for(int r = 0; r < 16; r++){
    const int row = (r & 3) + 8 * (r >> 2) + 4 * lhi;
    const int o = oBase + mw + row;
    if(o >= O1) continue;
    const float v = acc[r] + bias[o];
    if(o < 256)
      ctxb[((size_t)(b * 256 + o)) * N + n] = (ushort_t)f2bf(v);
    else
      gates[((size_t)(b * 4 + (o - 256))) * N + n] = v;
  }
}

// ---------------- fused depthwise chain v3 (fp32 LDS tiles) ----------
// 512 threads: thread = (row h, 8-wide col seg). fp32 LDS tiles, no row halos
// (predicated skip), col halo +-4 zeroed once. Output ctx_all written bf16
// IN PLACE over the input ctx buffer (block reads whole plane first).
constexpr int FSTR = 72;   // floats per row: 4 + 64 + 4; 288B, 16B-aligned

template<int K>
DEVFN void dw_stage(const float* src, const float* __restrict__ fw, int c,
                    int h, int w0, float* val){
  constexpr int R = K / 2;
  float acc[8];
  #pragma unroll
  for(int i = 0; i < 8; i++) acc[i] = 0.f;
  #pragma unroll
  for(int ky = 0; ky < K; ky++){
    const int r = h + ky - R;
    if((unsigned)r < 64u){
      const float* rp = &src[r * FSTR + w0];   // covers cols [w0-4, w0+12)
      float wnd[16];
      #pragma unroll
      for(int q = 0; q < 4; q++){
        float4 v4 = *(const float4*)(rp + q * 4);
        wnd[q*4+0] = v4.x; wnd[q*4+1] = v4.y; wnd[q*4+2] = v4.z; wnd[q*4+3] = v4.w;
      }
      #pragma unroll
      for(int kx = 0; kx < K; kx++){
        const float wv = fw[c * K * K + ky * K + kx];   // uniform -> SGPR
        #pragma unroll
        for(int i = 0; i < 8; i++)
          acc[i] = fmaf(wnd[i + kx + 4 - R], wv, acc[i]);
      }
    }
  }
  #pragma unroll
  for(int i = 0; i < 8; i++) val[i] = gelu_fast(acc[i]);
}

DEVFN void store_row(float* dst, int h, int w0, const float* val){
  float4 a, b;
  a.x = val[0]; a.y = val[1]; a.z = val[2]; a.w = val[3];
  b.x = val[4]; b.y = val[5]; b.z = val[6]; b.w = val[7];
  *(float4*)&dst[h * FSTR + w0 + 4] = a;
  *(float4*)&dst[h * FSTR + w0 + 8] = b;
}

__global__ __launch_bounds__(512, 8)
void k_dwchain(ushort_t* __restrict__ ctxb, const float* __restrict__ fw3,
               const float* __restrict__ fw5, const float* __restrict__ fw7,
               const float* __restrict__ gates){
  __shared__ __align__(16) float bufA[64 * FSTR];
  __shared__ __align__(16) float bufB[64 * FSTR];
  __shared__ float wred[8];
  const int tid = threadIdx.x;
  const int plane = blockIdx.x;
  const int b = plane >> 8;
  const int c = plane & 255;
  const int h  = tid >> 3;
  const int w0 = (tid & 7) * 8;
  const int nbase = h * 64 + w0;

  // zero col halos (rows have no stored halo)
  if(tid < 64){
    float4 z = {0.f, 0.f, 0.f, 0.f};
    *(float4*)&bufA[tid * FSTR] = z;  *(float4*)&bufA[tid * FSTR + 68] = z;
    *(float4*)&bufB[tid * FSTR] = z;  *(float4*)&bufB[tid * FSTR + 68] = z;
  }
  // stage input plane (bf16 global -> fp32 LDS)
  {
    bf16x8 iv = *(const bf16x8*)((const short*)ctxb + (size_t)plane * N + tid * 8);
    float4 a, bq;
    a.x  = bf2f((ushort_t)iv[0]); a.y  = bf2f((ushort_t)iv[1]);
    a.z  = bf2f((ushort_t)iv[2]); a.w  = bf2f((ushort_t)iv[3]);
    bq.x = bf2f((ushort_t)iv[4]); bq.y = bf2f((ushort_t)iv[5]);
    bq.z = bf2f((ushort_t)iv[6]); bq.w = bf2f((ushort_t)iv[7]);
    *(float4*)&bufA[h * FSTR + w0 + 4] = a;
    *(float4*)&bufA[h * FSTR + w0 + 8] = bq;
  }
  __syncthreads();

  float ctxp[8];
  #pragma unroll
  for(int i = 0; i < 8; i++) ctxp[i] = 0.f;
  float val[8];

  // stage 1: dw3 A->B
  dw_stage<3>(bufA, fw3, c, h, w0, val);
  {
    const float* gp = gates + ((size_t)(b * 4 + 0)) * N + nbase;
    float4 ga = *(const float4*)gp, gb = *(const float4*)(gp + 4);
    ctxp[0] = fmaf(val[0], ga.x, ctxp[0]); ctxp[1] = fmaf(val[1], ga.y, ctxp[1]);
    ctxp[2] = fmaf(val[2], ga.z, ctxp[2]); ctxp[3] = fmaf(val[3], ga.w, ctxp[3]);
    ctxp[4] = fmaf(val[4], gb.x, ctxp[4]); ctxp[5] = fmaf(val[5], gb.y, ctxp[5]);
    ctxp[6] = fmaf(val[6], gb.z, ctxp[6]); ctxp[7] = fmaf(val[7], gb.w, ctxp[7]);
    store_row(bufB, h, w0, val);
  }
  __syncthreads();

  // stage 2: dw5 B->A
  dw_stage<5>(bufB, fw5, c, h, w0, val);
  {
    const float* gp = gates + ((size_t)(b * 4 + 1)) * N + nbase;
    float4 ga = *(const float4*)gp, gb = *(const float4*)(gp + 4);
    ctxp[0] = fmaf(val[0], ga.x, ctxp[0]); ctxp[1] = fmaf(val[1], ga.y, ctxp[1]);
    ctxp[2] = fmaf(val[2], ga.z, ctxp[2]); ctxp[3] = fmaf(val[3], ga.w, ctxp[3]);
    ctxp[4] = fmaf(val[4], gb.x, ctxp[4]); ctxp[5] = fmaf(val[5], gb.y, ctxp[5]);
    ctxp[6] = fmaf(val[6], gb.z, ctxp[6]); ctxp[7] = fmaf(val[7], gb.w, ctxp[7]);
    store_row(bufA, h, w0, val);
  }
  __syncthreads();

  // stage 3: dw7 A->regs; plane mean of gelu output
  dw_stage<7>(bufA, fw7, c, h, w0, val);
  float lsum = 0.f;
  {
    const float* gp = gates + ((size_t)(b * 4 + 2)) * N + nbase;
    float4 ga = *(const float4*)gp, gb = *(const float4*)(gp + 4);
    ctxp[0] = fmaf(val[0], ga.x, ctxp[0]); ctxp[1] = fmaf(val[1], ga.y, ctxp[1]);
    ctxp[2] = fmaf(val[2], ga.z, ctxp[2]); ctxp[3] = fmaf(val[3], ga.w, ctxp[3]);
    ctxp[4] = fmaf(val[4], gb.x, ctxp[4]); ctxp[5] = fmaf(val[5], gb.y, ctxp[5]);
    ctxp[6] = fmaf(val[6], gb.z, ctxp[6]); ctxp[7] = fmaf(val[7], gb.w, ctxp[7]);
    #pragma unroll
    for(int i = 0; i < 8; i++) lsum += val[i];
  }
  // wave reduce then cross-wave
  #pragma unroll
  for(int off = 32; off > 0; off >>= 1) lsum += __shfl_xor(lsum, off, 64);
  if((tid & 63) == 0) wred[tid >> 6] = lsum;
  __syncthreads();
  float mean = 0.f;
  #pragma unroll
  for(int i = 0; i < 8; i++) mean += wred[i];
  mean *= (1.0f / 4096.0f);

  // ctx_all = ctxp + mean*g3 -> bf16, in place
  {
    const float* gp = gates + ((size_t)(b * 4 + 3)) * N + nbase;
    float4 ga = *(const float4*)gp, gb = *(const float4*)(gp + 4);
    bf16x8 ov;
    ov[0] = f2bf(fmaf(mean, ga.x, ctxp[0])); ov[1] = f2bf(fmaf(mean, ga.y, ctxp[1]));
    ov[2] = f2bf(fmaf(mean, ga.z, ctxp[2])); ov[3] = f2bf(fmaf(mean, ga.w, ctxp[3]));
    ov[4] = f2bf(fmaf(mean, gb.x, ctxp[4])); ov[5] = f2bf(fmaf(mean, gb.y, ctxp[5]));
    ov[6] = f2bf(fmaf(mean, gb.z, ctxp[6])); ov[7] = f2bf(fmaf(mean, gb.w, ctxp[7]));
    *(bf16x8*)((short*)ctxb + (size_t)plane * N + nbase) = ov;
  }
}

// ---------------- logits[b,n] = sum_c kw[c]*ctxall[b,c,n] + kb (bf16 read) ----
__global__ __launch_bounds__(256)
void k_logits(const ushort_t* __restrict__ P, const float* __restrict__ key_w,
              const float* __restrict__ key_b, float* __restrict__ logits){
  __shared__ float kw[256];
  __shared__ float part[512];
  int tid = threadIdx.x;
  kw[tid] = key_w[tid];
  __syncthreads();
  int b  = blockIdx.x >> 5;
  int n0 = (blockIdx.x & 31) * 128;
  int cpart = tid >> 6, pxp = tid & 63;       // pxp = pixel pair
  const ushort_t* pp = P + ((size_t)(b * 256 + cpart * 64)) * N + n0 + pxp * 2;
  float a0 = 0.f, a1 = 0.f;
  #pragma unroll 8
  for(int c = 0; c < 64; c++){
    unsigned u = *(const unsigned*)(pp + (size_t)c * N);
    float kwv = kw[cpart * 64 + c];
    a0 = fmaf(lo2f(u), kwv, a0);
    a1 = fmaf(hi2f(u), kwv, a1);
  }
  part[cpart * 128 + pxp * 2]     = a0;
  part[cpart * 128 + pxp * 2 + 1] = a1;
  __syncthreads();
  if(tid < 128){
    float l = part[tid] + part[128 + tid] + part[256 + tid] + part[384 + tid];
    logits[b * N + n0 + tid] = l + key_b[0];
  }
}

// ---------------- softmax over N per batch ----------
__global__ __launch_bounds__(256)
void k_softmax(float* __restrict__ kbuf){
  __shared__ float red[256];
  int b = blockIdx.x, tid = threadIdx.x;
  float v[16];
  float m = -1e30f;
  #pragma unroll
  for(int i = 0; i < 16; i++){
    v[i] = kbuf[b * N + tid + i * 256];
    m = fmaxf(m, v[i]);
  }
  red[tid] = m; __syncthreads();
  for(int s = 128; s > 0; s >>= 1){
    if(tid < s) red[tid] = fmaxf(red[tid], red[tid + s]);
    __syncthreads();
  }
  m = red[0]; __syncthreads();
  float ssum = 0.f;
  #pragma unroll
  for(int i = 0; i < 16; i++){ v[i] = __expf(v[i] - m); ssum += v[i]; }
  red[tid] = ssum; __syncthreads();
  for(int s = 128; s > 0; s >>= 1){
    if(tid < s) red[tid] += red[tid + s];
    __syncthreads();
  }
  float inv = 1.0f / red[0];
  #pragma unroll
  for(int i = 0; i < 16; i++)
    kbuf[b * N + tid + i * 256] = v[i] * inv;
}

// ---------------- qk[b,c] = sum_n ctxall[b,c,n]*k[b,n] (bf16 read) ----------
__global__ __launch_bounds__(256)
void k_qk(const ushort_t* __restrict__ P, const float* __restrict__ kbuf,
          float* __restrict__ qk){
  __shared__ float red[256];
  int plane = blockIdx.x, tid = threadIdx.x;
  int b = plane >> 8;
  const unsigned* pp = (const unsigned*)(P + (size_t)plane * N);
  const float2* kp = (const float2*)(kbuf + b * N);
  float acc = 0.f;
  #pragma unroll
  for(int i = 0; i < 8; i++){
    int idx = tid + i * 256;
    unsigned u = pp[idx];
    float2 kk = kp[idx];
    acc = fmaf(lo2f(u), kk.x, acc);
    acc = fmaf(hi2f(u), kk.y, acc);
  }
  red[tid] = acc; __syncthreads();
  for(int s = 128; s > 0; s >>= 1){
    if(tid < s) red[tid] += red[tid + s];
    __syncthreads();
  }
  if(tid == 0) qk[plane] = red[0];
}

// ---------------- v pipeline per batch ----------
__global__ __launch_bounds__(256)
void k_v(const float* __restrict__ qk, const float* __restrict__ v1w,
         const float* __restrict__ v1b, const float* __restrict__ lnw,
         const float* __restrict__ lnb, const float* __restrict__ v2w,
         const float* __restrict__ v2b, float* __restrict__ vout){
  int b = blockIdx.x, tid = threadIdx.x;
  __shared__ float qs[256];
  __shared__ float part[256];
  __shared__ float v1s[16];
  __shared__ float vr[16];
  __shared__ float stats[2];
  qs[tid] = qk[b * 256 + tid];
  __syncthreads();
  int oc = tid >> 4, ln = tid & 15;
  float p = 0.f;
  #pragma unroll
  for(int j = 0; j < 16; j++){
    int cc = ln + j * 16;
    p = fmaf(v1w[oc * 256 + cc], qs[cc], p);
  }
  part[tid] = p;
  __syncthreads();
  if(tid < 16){
    float s = v1b[tid];
    for(int j = 0; j < 16; j++) s += part[tid * 16 + j];
    v1s[tid] = s;
  }
  __syncthreads();
  if(tid == 0){
    float mu = 0.f;
    for(int i = 0; i < 16; i++) mu += v1s[i];
    mu *= (1.f / 16.f);
    float var = 0.f;
    for(int i = 0; i < 16; i++){ float d = v1s[i] - mu; var += d * d; }
    var *= (1.f / 16.f);
    stats[0] = mu; stats[1] = rsqrtf(var + 1e-5f);
  }
  __syncthreads();
  if(tid < 16){
    float vv = (v1s[tid] - stats[0]) * stats[1] * lnw[tid] + lnb[tid];
    vr[tid] = fmaxf(vv, 0.f);
  }
  __syncthreads();
  float o = v2b[tid];
  #pragma unroll
  for(int j = 0; j < 16; j++) o = fmaf(v2w[tid * 16 + j], vr[j], o);
  vout[b * 256 + tid] = o;
}

// ---------------- out = f32(ctxall_bf16) + vout (pure write) ----------
__global__ __launch_bounds__(256)
void k_final(float* __restrict__ out, const ushort_t* __restrict__ ctxb,
             const float* __restrict__ vout){
  int idx8 = blockIdx.x * 256 + threadIdx.x;       // 8-px group
  int plane = idx8 >> 9;
  int off = (idx8 & 511) * 8;
  bf16x8 v = *(const bf16x8*)((const short*)ctxb + (size_t)plane * N + off);
  float vv = vout[plane];
  float4 o0, o1;
  o0.x = bf2f((ushort_t)v[0]) + vv; o0.y = bf2f((ushort_t)v[1]) + vv;
  o0.z = bf2f((ushort_t)v[2]) + vv; o0.w = bf2f((ushort_t)v[3]) + vv;
  o1.x = bf2f((ushort_t)v[4]) + vv; o1.y = bf2f((ushort_t)v[5]) + vv;
  o1.z = bf2f((ushort_t)v[6]) + vv; o1.w = bf2f((ushort_t)v[7]) + vv;
  float* op = out + (size_t)plane * N + off;
  *(float4*)op = o0;
  *(float4*)(op + 4) = o1;
}

extern "C" void kernel_launch(void* const* d_in, const int* in_sizes, int n_in,
                              void* d_out, int out_size, void* d_ws, size_t ws_size,
                              hipStream_t stream){
  const float* x      = (const float*)d_in[0];
  const float* conv_w = (const float*)d_in[1];
  const float* conv_b = (const float*)d_in[2];
  const float* fw3    = (const float*)d_in[3];
  const float* fw5    = (const float*)d_in[4];
  const float* fw7    = (const float*)d_in[5];
  const float* key_w  = (const float*)d_in[6];
  const float* key_b  = (const float*)d_in[7];
  const float* v1_w   = (const float*)d_in[8];
  const float* v1_b   = (const float*)d_in[9];
  const float* ln_w   = (const float*)d_in[10];
  const float* ln_b   = (const float*)d_in[11];
  const float* v2_w   = (const float*)d_in[12];
  const float* v2_b   = (const float*)d_in[13];
  float* out = (float*)d_out;

  const size_t PL = (size_t)B * C * N;     // 16,777,216 elements
  char* p = (char*)d_ws;
  ushort_t* ctxb = (ushort_t*)p;  p += PL * sizeof(ushort_t);          // 32 MB
  float* gates   = (float*)p;     p += (size_t)B * 4 * N * sizeof(float);
  float* kbuf    = (float*)p;     p += (size_t)B * N * sizeof(float);
  float* qkb     = (float*)p;     p += (size_t)B * C * sizeof(float);
  float* vout    = (float*)p;

  // 1. conv1x1 via bf16 MFMA -> ctxb (bf16, 256 ch) + gates (f32, 4 ch)
  k_conv1_mfma<<<dim3(1024, 5), 256, 0, stream>>>(x, conv_w, conv_b, ctxb, gates);
  // 2. fused dw3/dw5/dw7 chain -> ctxb overwritten with bf16 ctx_all
  k_dwchain<<<B * C, 512, 0, stream>>>(ctxb, fw3, fw5, fw7, gates);
  // 3. logits (reads bf16 ctx_all)
  k_logits<<<512, 256, 0, stream>>>(ctxb, key_w, key_b, kbuf);
  // 4. softmax
  k_softmax<<<B, 256, 0, stream>>>(kbuf);
  // 5. qk (reads bf16 ctx_all)
  k_qk<<<B * C, 256, 0, stream>>>(ctxb, kbuf, qkb);
  // 6. v pipeline
  k_v<<<B, 256, 0, stream>>>(qkb, v1_w, v1_b, ln_w, ln_b, v2_w, v2_b, vout);
  // 7. final: out = f32(ctx_all) + v broadcast (pure write)
  k_final<<<8192, 256, 0, stream>>>(out, ctxb, vout);
}

// Round 6
// 296.574 us; speedup vs baseline: 1.3546x; 1.3546x over previous
//
#include <hip/hip_runtime.h>

#define DEVFN __device__ __forceinline__

constexpr int B  = 16;
constexpr int C  = 256;
constexpr int N  = 64 * 64;     // 4096
constexpr int O1 = C + 4;       // 260

typedef __attribute__((ext_vector_type(8)))  short bf16x8;
typedef __attribute__((ext_vector_type(4)))  short bf16x4;
typedef __attribute__((ext_vector_type(16))) float f32x16;
typedef unsigned short ushort_t;

DEVFN short f2bf(float f){
  union { float f; unsigned u; } p; p.f = f;
  unsigned r = p.u + 0x7fffu + ((p.u >> 16) & 1u);   // RNE
  return (short)(r >> 16);
}
DEVFN unsigned pack2(float lo, float hi){
  return (unsigned)(ushort_t)f2bf(lo) | ((unsigned)(ushort_t)f2bf(hi) << 16);
}
DEVFN float lo2f(unsigned u){ union{unsigned u; float f;} p; p.u = u << 16; return p.f; }
DEVFN float hi2f(unsigned u){ union{unsigned u; float f;} p; p.u = u & 0xffff0000u; return p.f; }
DEVFN float bf2f(ushort_t s){ union{unsigned u; float f;} p; p.u = (unsigned)s << 16; return p.f; }

// tanh-form gelu with raw v_rcp: max err ~5e-4
DEVFN float gelu_fast(float x){
  float y = 1.5957691216f * fmaf(0.044715f * x * x, x, x);
  float s = __builtin_amdgcn_rcpf(1.0f + __expf(-y));
  return x * s;
}

// ---------------- K1: conv1x1 as bf16 MFMA GEMM, reg-prefetch staging -------
// Block 64o x 64px, 4 waves each one 32x32 tile. K chunked by 128; next
// chunk's W/X staged into packed-bf16 regs BEFORE current chunk's MFMAs so
// global latency overlaps compute (reg double-buffer, single LDS buffer).
__global__ __launch_bounds__(256, 4)
void k_conv1_mfma(const float* __restrict__ x, const float* __restrict__ w,
                  const float* __restrict__ bias, ushort_t* __restrict__ ctxb,
                  float* __restrict__ gates){
  __shared__ __align__(16) short wlds[16 * 64 * 8];   // 16KB: [kg][m][8]
  __shared__ __align__(16) short xlds[16 * 64 * 8];   // 16KB: [kg][n][8]
  const int tid  = threadIdx.x;
  const int wv   = tid >> 6;
  const int lane = tid & 63;
  const int l31  = lane & 31;
  const int lhi  = lane >> 5;
  const int oBase = blockIdx.y * 64;
  const int pg0   = blockIdx.x * 64;
  const int b  = pg0 >> 12;
  const int n0 = pg0 & 4095;
  const int mw = (wv >> 1) * 32;
  const int nw = (wv & 1) * 32;

  const int rstage = tid & 63;
  const int kg0    = (tid >> 6) * 4;
  const int oS     = oBase + rstage;
  const float* wpb = w + oS * 256;
  const float* xpb = x + (size_t)b * C * N + n0 + rstage;

  f32x16 acc;
  #pragma unroll
  for(int r = 0; r < 16; r++) acc[r] = 0.f;

  unsigned wpkA[16], xpkA[16], wpkB[16], xpkB[16];

  // ---- load helpers (macro-free, inlined by unroll)
  auto loadW = [&](int kc, unsigned* wpk){
    #pragma unroll
    for(int t = 0; t < 4; t++){
      const int kg = kg0 + t;
      if(oS < O1){
        const float4 f0 = *(const float4*)(wpb + kc + kg * 8);
        const float4 f1 = *(const float4*)(wpb + kc + kg * 8 + 4);
        wpk[t*4+0] = pack2(f0.x, f0.y); wpk[t*4+1] = pack2(f0.z, f0.w);
        wpk[t*4+2] = pack2(f1.x, f1.y); wpk[t*4+3] = pack2(f1.z, f1.w);
      } else {
        wpk[t*4+0] = wpk[t*4+1] = wpk[t*4+2] = wpk[t*4+3] = 0u;
      }
    }
  };
  auto loadX = [&](int kc, unsigned* xpk){
    #pragma unroll
    for(int t = 0; t < 4; t++){
      const int kg = kg0 + t;
      const float* xp = xpb + (size_t)(kc + kg * 8) * N;
      float f[8];
      #pragma unroll
      for(int j = 0; j < 8; j++) f[j] = xp[(size_t)j * N];
      xpk[t*4+0] = pack2(f[0], f[1]); xpk[t*4+1] = pack2(f[2], f[3]);
      xpk[t*4+2] = pack2(f[4], f[5]); xpk[t*4+3] = pack2(f[6], f[7]);
    }
  };
  auto storeLDS = [&](const unsigned* wpk, const unsigned* xpk){
    #pragma unroll
    for(int t = 0; t < 4; t++){
      const int kg = kg0 + t;
      uint4 wq; wq.x = wpk[t*4+0]; wq.y = wpk[t*4+1]; wq.z = wpk[t*4+2]; wq.w = wpk[t*4+3];
      uint4 xq; xq.x = xpk[t*4+0]; xq.y = xpk[t*4+1]; xq.z = xpk[t*4+2]; xq.w = xpk[t*4+3];
      *(uint4*)&wlds[(kg * 64 + rstage) * 8] = wq;
      *(uint4*)&xlds[(kg * 64 + rstage) * 8] = xq;
    }
  };
  auto mfma8 = [&](){
    #pragma unroll
    for(int ks = 0; ks < 8; ks++){
      const int kg = ks * 2 + lhi;
      bf16x8 af  = *(const bf16x8*)&wlds[(kg * 64 + mw + l31) * 8];
      bf16x8 bfr = *(const bf16x8*)&xlds[(kg * 64 + nw + l31) * 8];
      acc = __builtin_amdgcn_mfma_f32_32x32x16_bf16(af, bfr, acc, 0, 0, 0);
    }
  };

  // ---- pipelined 2-chunk K loop
  loadW(0, wpkA); loadX(0, xpkA);
  storeLDS(wpkA, xpkA);
  __syncthreads();
  loadW(128, wpkB); loadX(128, xpkB);   // in flight during chunk-0 MFMAs
  mfma8();
  __syncthreads();
  storeLDS(wpkB, xpkB);
  __syncthreads();
  mfma8();

  // ---- epilogue: C/D layout col=lane&31, row=(r&3)+8*(r>>2)+4*(lane>>5)
  const int n = n0 + nw + l31;
  #pragma unroll
  for(int r = 0; r < 16; r++){
    const int row = (r & 3) + 8 * (r >> 2) + 4 * lhi;
    const int o = oBase + mw + row;
    if(o >= O1) continue;
    const float v = acc[r] + bias[o];
    if(o < 256)
      ctxb[((size_t)(b * 256 + o)) * N + n] = (ushort_t)f2bf(v);
    else
      gates[((size_t)(b * 4 + (o - 256))) * N + n] = v;
  }
}

// ---------------- fused depthwise chain (R4-proven bf16 LDS tiles) ----------
// 512 threads: thread = (row h, 8-wide col seg). bf16 LDS tiles, no row halos
// (predicated skip), col halo +-4 zeroed once. Weights via uniform scalar
// loads. ctx_all written bf16 IN PLACE over the ctx buffer.
// NOTE: row stride 72 shorts = 36 dwords == 4 (mod 32 banks) -> near-conflict-
// free for b128 reads; do NOT change to fp32/72-float stride (8 mod 32 -> 16-way).
constexpr int SSTR = 72;

DEVFN void unpack16(const short* p, float* wnd){
  uint4 a = *(const uint4*)p;
  uint4 b = *(const uint4*)(p + 8);
  unsigned ua[8] = {a.x, a.y, a.z, a.w, b.x, b.y, b.z, b.w};
  #pragma unroll
  for(int d = 0; d < 8; d++){ wnd[2*d] = lo2f(ua[d]); wnd[2*d+1] = hi2f(ua[d]); }
}

template<int K>
DEVFN void dw_stage(const short* src, const float* __restrict__ fw, int c,
                    int h, int w0, float* val){
  constexpr int R = K / 2;
  float acc[8];
  #pragma unroll
  for(int i = 0; i < 8; i++) acc[i] = 0.f;
  #pragma unroll
  for(int ky = 0; ky < K; ky++){
    const int r = h + ky - R;
    if((unsigned)r < 64u){
      float wnd[16];
      unpack16(&src[r * SSTR + w0], wnd);       // covers cols [w0-4, w0+12)
      #pragma unroll
      for(int kx = 0; kx < K; kx++){
        const float wv = fw[c * K * K + ky * K + kx];   // uniform -> SGPR
        #pragma unroll
        for(int i = 0; i < 8; i++)
          acc[i] = fmaf(wnd[i + kx + 4 - R], wv, acc[i]);
      }
    }
  }
  #pragma unroll
  for(int i = 0; i < 8; i++) val[i] = gelu_fast(acc[i]);
}

DEVFN void store_row(short* dst, int h, int w0, const float* val){
  bf16x4 lo, hi;
  #pragma unroll
  for(int i = 0; i < 4; i++){ lo[i] = f2bf(val[i]); hi[i] = f2bf(val[i + 4]); }
  *(bf16x4*)&dst[h * SSTR + w0 + 4] = lo;
  *(bf16x4*)&dst[h * SSTR + w0 + 8] = hi;
}

__global__ __launch_bounds__(512, 8)
void k_dwchain(ushort_t* __restrict__ ctxb, const float* __restrict__ fw3,
               const float* __restrict__ fw5, const float* __restrict__ fw7,
               const float* __restrict__ gates){
  __shared__ __align__(16) short bufA[64 * SSTR];
  __shared__ __align__(16) short bufB[64 * SSTR];
  __shared__ float wred[8];
  const int tid = threadIdx.x;
  const int plane = blockIdx.x;
  const int b = plane >> 8;
  const int c = plane & 255;
  const int h  = tid >> 3;
  const int w0 = (tid & 7) * 8;
  const int nbase = h * 64 + w0;

  if(tid < 64){
    bf16x4 z = {0, 0, 0, 0};
    *(bf16x4*)&bufA[tid * SSTR] = z;  *(bf16x4*)&bufA[tid * SSTR + 68] = z;
    *(bf16x4*)&bufB[tid * SSTR] = z;  *(bf16x4*)&bufB[tid * SSTR + 68] = z;
  }
  {
    bf16x8 iv = *(const bf16x8*)((const short*)ctxb + (size_t)plane * N + tid * 8);
    bf16x4 lo, hi;
    #pragma unroll
    for(int j = 0; j < 4; j++){ lo[j] = iv[j]; hi[j] = iv[j + 4]; }
    *(bf16x4*)&bufA[h * SSTR + w0 + 4] = lo;
    *(bf16x4*)&bufA[h * SSTR + w0 + 8] = hi;
  }
  __syncthreads();

  float ctxp[8];
  #pragma unroll
  for(int i = 0; i < 8; i++) ctxp[i] = 0.f;
  float val[8];

  // stage 1: dw3 A->B
  dw_stage<3>(bufA, fw3, c, h, w0, val);
  {
    const float* gp = gates + ((size_t)(b * 4 + 0)) * N + nbase;
    float4 ga = *(const float4*)gp, gb = *(const float4*)(gp + 4);
    ctxp[0] = fmaf(val[0], ga.x, ctxp[0]); ctxp[1] = fmaf(val[1], ga.y, ctxp[1]);
    ctxp[2] = fmaf(val[2], ga.z, ctxp[2]); ctxp[3] = fmaf(val[3], ga.w, ctxp[3]);
    ctxp[4] = fmaf(val[4], gb.x, ctxp[4]); ctxp[5] = fmaf(val[5], gb.y, ctxp[5]);
    ctxp[6] = fmaf(val[6], gb.z, ctxp[6]); ctxp[7] = fmaf(val[7], gb.w, ctxp[7]);
    store_row(bufB, h, w0, val);
  }
  __syncthreads();

  // stage 2: dw5 B->A
  dw_stage<5>(bufB, fw5, c, h, w0, val);
  {
    const float* gp = gates + ((size_t)(b * 4 + 1)) * N + nbase;
    float4 ga = *(const float4*)gp, gb = *(const float4*)(gp + 4);
    ctxp[0] = fmaf(val[0], ga.x, ctxp[0]); ctxp[1] = fmaf(val[1], ga.y, ctxp[1]);
    ctxp[2] = fmaf(val[2], ga.z, ctxp[2]); ctxp[3] = fmaf(val[3], ga.w, ctxp[3]);
    ctxp[4] = fmaf(val[4], gb.x, ctxp[4]); ctxp[5] = fmaf(val[5], gb.y, ctxp[5]);
    ctxp[6] = fmaf(val[6], gb.z, ctxp[6]); ctxp[7] = fmaf(val[7], gb.w, ctxp[7]);
    store_row(bufA, h, w0, val);
  }
  __syncthreads();

  // stage 3: dw7 A->regs; plane mean of gelu output
  dw_stage<7>(bufA, fw7, c, h, w0, val);
  float lsum = 0.f;
  {
    const float* gp = gates + ((size_t)(b * 4 + 2)) * N + nbase;
    float4 ga = *(const float4*)gp, gb = *(const float4*)(gp + 4);
    ctxp[0] = fmaf(val[0], ga.x, ctxp[0]); ctxp[1] = fmaf(val[1], ga.y, ctxp[1]);
    ctxp[2] = fmaf(val[2], ga.z, ctxp[2]); ctxp[3] = fmaf(val[3], ga.w, ctxp[3]);
    ctxp[4] = fmaf(val[4], gb.x, ctxp[4]); ctxp[5] = fmaf(val[5], gb.y, ctxp[5]);
    ctxp[6] = fmaf(val[6], gb.z, ctxp[6]); ctxp[7] = fmaf(val[7], gb.w, ctxp[7]);
    #pragma unroll
    for(int i = 0; i < 8; i++) lsum += val[i];
  }
  #pragma unroll
  for(int off = 32; off > 0; off >>= 1) lsum += __shfl_xor(lsum, off, 64);
  if((tid & 63) == 0) wred[tid >> 6] = lsum;
  __syncthreads();
  float mean = 0.f;
  #pragma unroll
  for(int i = 0; i < 8; i++) mean += wred[i];
  mean *= (1.0f / 4096.0f);

  // ctx_all = ctxp + mean*g3 -> bf16, in place
  {
    const float* gp = gates + ((size_t)(b * 4 + 3)) * N + nbase;
    float4 ga = *(const float4*)gp, gb = *(const float4*)(gp + 4);
    bf16x8 ov;
    ov[0] = f2bf(fmaf(mean, ga.x, ctxp[0])); ov[1] = f2bf(fmaf(mean, ga.y, ctxp[1]));
    ov[2] = f2bf(fmaf(mean, ga.z, ctxp[2])); ov[3] = f2bf(fmaf(mean, ga.w, ctxp[3]));
    ov[4] = f2bf(fmaf(mean, gb.x, ctxp[4])); ov[5] = f2bf(fmaf(mean, gb.y, ctxp[5]));
    ov[6] = f2bf(fmaf(mean, gb.z, ctxp[6])); ov[7] = f2bf(fmaf(mean, gb.w, ctxp[7]));
    *(bf16x8*)((short*)ctxb + (size_t)plane * N + nbase) = ov;
  }
}

// ---------------- logits[b,n] = sum_c kw[c]*ctxall[b,c,n] + kb (bf16 read) ----
__global__ __launch_bounds__(256)
void k_logits(const ushort_t* __restrict__ P, const float* __restrict__ key_w,
              const float* __restrict__ key_b, float* __restrict__ logits){
  __shared__ float kw[256];
  __shared__ float part[512];
  int tid = threadIdx.x;
  kw[tid] = key_w[tid];
  __syncthreads();
  int b  = blockIdx.x >> 5;
  int n0 = (blockIdx.x & 31) * 128;
  int cpart = tid >> 6, pxp = tid & 63;
  const ushort_t* pp = P + ((size_t)(b * 256 + cpart * 64)) * N + n0 + pxp * 2;
  float a0 = 0.f, a1 = 0.f;
  #pragma unroll 8
  for(int c = 0; c < 64; c++){
    unsigned u = *(const unsigned*)(pp + (size_t)c * N);
    float kwv = kw[cpart * 64 + c];
    a0 = fmaf(lo2f(u), kwv, a0);
    a1 = fmaf(hi2f(u), kwv, a1);
  }
  part[cpart * 128 + pxp * 2]     = a0;
  part[cpart * 128 + pxp * 2 + 1] = a1;
  __syncthreads();
  if(tid < 128){
    float l = part[tid] + part[128 + tid] + part[256 + tid] + part[384 + tid];
    logits[b * N + n0 + tid] = l + key_b[0];
  }
}

// ---------------- softmax over N per batch (1024 thr, shfl reduce) ----------
__global__ __launch_bounds__(1024)
void k_softmax(float* __restrict__ kbuf){
  __shared__ float wred[16];
  int b = blockIdx.x, tid = threadIdx.x;
  const int wave = tid >> 6, lane = tid & 63;
  float v[4];
  float m = -1e30f;
  #pragma unroll
  for(int i = 0; i < 4; i++){
    v[i] = kbuf[b * N + tid + i * 1024];
    m = fmaxf(m, v[i]);
  }
  #pragma unroll
  for(int off = 32; off > 0; off >>= 1) m = fmaxf(m, __shfl_xor(m, off, 64));
  if(lane == 0) wred[wave] = m;
  __syncthreads();
  float mm = -1e30f;
  #pragma unroll
  for(int i = 0; i < 16; i++) mm = fmaxf(mm, wred[i]);
  __syncthreads();
  float s = 0.f;
  #pragma unroll
  for(int i = 0; i < 4; i++){ v[i] = __expf(v[i] - mm); s += v[i]; }
  #pragma unroll
  for(int off = 32; off > 0; off >>= 1) s += __shfl_xor(s, off, 64);
  if(lane == 0) wred[wave] = s;
  __syncthreads();
  float tot = 0.f;
  #pragma unroll
  for(int i = 0; i < 16; i++) tot += wred[i];
  float inv = 1.0f / tot;
  #pragma unroll
  for(int i = 0; i < 4; i++)
    kbuf[b * N + tid + i * 1024] = v[i] * inv;
}

// ---------------- qk[b,c] = sum_n ctxall[b,c,n]*k[b,n] (bf16 read) ----------
__global__ __launch_bounds__(256)
void k_qk(const ushort_t* __restrict__ P, const float* __restrict__ kbuf,
          float* __restrict__ qk){
  __shared__ float red[256];
  int plane = blockIdx.x, tid = threadIdx.x;
  int b = plane >> 8;
  const unsigned* pp = (const unsigned*)(P + (size_t)plane * N);
  const float2* kp = (const float2*)(kbuf + b * N);
  float acc = 0.f;
  #pragma unroll
  for(int i = 0; i < 8; i++){
    int idx = tid + i * 256;
    unsigned u = pp[idx];
    float2 kk = kp[idx];
    acc = fmaf(lo2f(u), kk.x, acc);
    acc = fmaf(hi2f(u), kk.y, acc);
  }
  red[tid] = acc; __syncthreads();
  for(int s = 128; s > 0; s >>= 1){
    if(tid < s) red[tid] += red[tid + s];
    __syncthreads();
  }
  if(tid == 0) qk[plane] = red[0];
}

// ---------------- v pipeline per batch ----------
__global__ __launch_bounds__(256)
void k_v(const float* __restrict__ qk, const float* __restrict__ v1w,
         const float* __restrict__ v1b, const float* __restrict__ lnw,
         const float* __restrict__ lnb, const float* __restrict__ v2w,
         const float* __restrict__ v2b, float* __restrict__ vout){
  int b = blockIdx.x, tid = threadIdx.x;
  __shared__ float qs[256];
  __shared__ float part[256];
  __shared__ float v1s[16];
  __shared__ float vr[16];
  __shared__ float stats[2];
  qs[tid] = qk[b * 256 + tid];
  __syncthreads();
  int oc = tid >> 4, ln = tid & 15;
  float p = 0.f;
  #pragma unroll
  for(int j = 0; j < 16; j++){
    int cc = ln + j * 16;
    p = fmaf(v1w[oc * 256 + cc], qs[cc], p);
  }
  part[tid] = p;
  __syncthreads();
  if(tid < 16){
    float s = v1b[tid];
    for(int j = 0; j < 16; j++) s += part[tid * 16 + j];
    v1s[tid] = s;
  }
  __syncthreads();
  if(tid == 0){
    float mu = 0.f;
    for(int i = 0; i < 16; i++) mu += v1s[i];
    mu *= (1.f / 16.f);
    float var = 0.f;
    for(int i = 0; i < 16; i++){ float d = v1s[i] - mu; var += d * d; }
    var *= (1.f / 16.f);
    stats[0] = mu; stats[1] = rsqrtf(var + 1e-5f);
  }
  __syncthreads();
  if(tid < 16){
    float vv = (v1s[tid] - stats[0]) * stats[1] * lnw[tid] + lnb[tid];
    vr[tid] = fmaxf(vv, 0.f);
  }
  __syncthreads();
  float o = v2b[tid];
  #pragma unroll
  for(int j = 0; j < 16; j++) o = fmaf(v2w[tid * 16 + j], vr[j], o);
  vout[b * 256 + tid] = o;
}

// ---------------- out = f32(ctxall_bf16) + vout (pure write) ----------
__global__ __launch_bounds__(256)
void k_final(float* __restrict__ out, const ushort_t* __restrict__ ctxb,
             const float* __restrict__ vout){
  int idx8 = blockIdx.x * 256 + threadIdx.x;
  int plane = idx8 >> 9;
  int off = (idx8 & 511) * 8;
  bf16x8 v = *(const bf16x8*)((const short*)ctxb + (size_t)plane * N + off);
  float vv = vout[plane];
  float4 o0, o1;
  o0.x = bf2f((ushort_t)v[0]) + vv; o0.y = bf2f((ushort_t)v[1]) + vv;
  o0.z = bf2f((ushort_t)v[2]) + vv; o0.w = bf2f((ushort_t)v[3]) + vv;
  o1.x = bf2f((ushort_t)v[4]) + vv; o1.y = bf2f((ushort_t)v[5]) + vv;
  o1.z = bf2f((ushort_t)v[6]) + vv; o1.w = bf2f((ushort_t)v[7]) + vv;
  float* op = out + (size_t)plane * N + off;
  *(float4*)op = o0;
  *(float4*)(op + 4) = o1;
}

extern "C" void kernel_launch(void* const* d_in, const int* in_sizes, int n_in,
                              void* d_out, int out_size, void* d_ws, size_t ws_size,
                              hipStream_t stream){
  const float* x      = (const float*)d_in[0];
  const float* conv_w = (const float*)d_in[1];
  const float* conv_b = (const float*)d_in[2];
  const float* fw3    = (const float*)d_in[3];
  const float* fw5    = (const float*)d_in[4];
  const float* fw7    = (const float*)d_in[5];
  const float* key_w  = (const float*)d_in[6];
  const float* key_b  = (const float*)d_in[7];
  const float* v1_w   = (const float*)d_in[8];
  const float* v1_b   = (const float*)d_in[9];
  const float* ln_w   = (const float*)d_in[10];
  const float* ln_b   = (const float*)d_in[11];
  const float* v2_w   = (const float*)d_in[12];
  const float* v2_b   = (const float*)d_in[13];
  float* out = (float*)d_out;

  const size_t PL = (size_t)B * C * N;     // 16,777,216 elements
  char* p = (char*)d_ws;
  ushort_t* ctxb = (ushort_t*)p;  p += PL * sizeof(ushort_t);          // 32 MB
  float* gates   = (float*)p;     p += (size_t)B * 4 * N * sizeof(float);
  float* kbuf    = (float*)p;     p += (size_t)B * N * sizeof(float);
  float* qkb     = (float*)p;     p += (size_t)B * C * sizeof(float);
  float* vout    = (float*)p;

  // 1. conv1x1 via bf16 MFMA (reg-prefetch staging)
  k_conv1_mfma<<<dim3(1024, 5), 256, 0, stream>>>(x, conv_w, conv_b, ctxb, gates);
  // 2. fused dw3/dw5/dw7 chain -> ctxb overwritten with bf16 ctx_all
  k_dwchain<<<B * C, 512, 0, stream>>>(ctxb, fw3, fw5, fw7, gates);
  // 3. logits (reads bf16 ctx_all)
  k_logits<<<512, 256, 0, stream>>>(ctxb, key_w, key_b, kbuf);
  // 4. softmax
  k_softmax<<<B, 1024, 0, stream>>>(kbuf);
  // 5. qk (reads bf16 ctx_all)
  k_qk<<<B * C, 256, 0, stream>>>(ctxb, kbuf, qkb);
  // 6. v pipeline
  k_v<<<B, 256, 0, stream>>>(qkb, v1_w, v1_b, ln_w, ln_b, v2_w, v2_b, vout);
  // 7. final: out = f32(ctx_all) + v broadcast (pure write)
  k_final<<<8192, 256, 0, stream>>>(out, ctxb, vout);
}

// Round 7
// 283.605 us; speedup vs baseline: 1.4165x; 1.0457x over previous
//
#include <hip/hip_runtime.h>

#define DEVFN __device__ __forceinline__

constexpr int B  = 16;
constexpr int C  = 256;
constexpr int N  = 64 * 64;     // 4096
constexpr int O1 = C + 4;       // 260

typedef __attribute__((ext_vector_type(8)))  short bf16x8;
typedef __attribute__((ext_vector_type(4)))  short bf16x4;
typedef __attribute__((ext_vector_type(16))) float f32x16;
typedef unsigned short ushort_t;

DEVFN short f2bf(float f){
  union { float f; unsigned u; } p; p.f = f;
  unsigned r = p.u + 0x7fffu + ((p.u >> 16) & 1u);   // RNE
  return (short)(r >> 16);
}
DEVFN unsigned pack2(float lo, float hi){
  return (unsigned)(ushort_t)f2bf(lo) | ((unsigned)(ushort_t)f2bf(hi) << 16);
}
DEVFN float lo2f(unsigned u){ union{unsigned u; float f;} p; p.u = u << 16; return p.f; }
DEVFN float hi2f(unsigned u){ union{unsigned u; float f;} p; p.u = u & 0xffff0000u; return p.f; }
DEVFN float bf2f(ushort_t s){ union{unsigned u; float f;} p; p.u = (unsigned)s << 16; return p.f; }

// tanh-form gelu with raw v_rcp: max err ~5e-4
DEVFN float gelu_fast(float x){
  float y = 1.5957691216f * fmaf(0.044715f * x * x, x, x);
  float s = __builtin_amdgcn_rcpf(1.0f + __expf(-y));
  return x * s;
}

// ---------------- K0: pre-convert conv_w to zero-padded bf16 [320][256] -----
__global__ __launch_bounds__(256)
void k_wbf(const float* __restrict__ w, ushort_t* __restrict__ wbf){
  int idx = blockIdx.x * 256 + threadIdx.x;   // 320*256 = 81920
  int o = idx >> 8, cc = idx & 255;
  wbf[idx] = (o < O1) ? (ushort_t)f2bf(w[o * 256 + cc]) : (ushort_t)0;
}

// ---------------- K1: conv1x1 MFMA GEMM, single-pass-over-x ----------
// Block = 64 px x 320 padded outputs. 4 waves; each wave owns 5 32x32 acc
// tiles (n-col = wave&1, m-tiles (wave>>1)+2t). K chunked by 64. x read
// EXACTLY ONCE from HBM (no o-tile sweeps). W staged from pre-converted bf16
// (L2-hot, pure copy). X regs prefetched for chunk i+1 during chunk-i MFMAs.
// LDS frag-major [kg][row][8] -> uniform bank coverage (0 conflicts, R6).
__global__ __launch_bounds__(256, 3)
void k_conv1_mfma(const float* __restrict__ x, const ushort_t* __restrict__ wbf,
                  const float* __restrict__ bias, ushort_t* __restrict__ ctxb,
                  float* __restrict__ gates){
  __shared__ __align__(16) short wlds[8 * 320 * 8];   // 40KB [kg][m][8]
  __shared__ __align__(16) short xlds[8 * 64 * 8];    //  8KB [kg][n][8]
  __shared__ float sbias[320];
  const int tid  = threadIdx.x;
  const int wave = tid >> 6;
  const int lane = tid & 63;
  const int l31  = lane & 31;
  const int lhi  = lane >> 5;
  const int pg0  = blockIdx.x * 64;
  const int b    = pg0 >> 12;
  const int n0   = pg0 & 4095;
  const int nwv  = (wave & 1) * 32;
  const int mrow = wave >> 1;

  sbias[tid] = bias[tid];
  if(tid < 64) sbias[256 + tid] = (256 + tid < O1) ? bias[256 + tid] : 0.f;

  const float* xpb = x + (size_t)b * C * N + n0;

  f32x16 acc[5];
  #pragma unroll
  for(int t = 0; t < 5; t++)
    #pragma unroll
    for(int r = 0; r < 16; r++) acc[t][r] = 0.f;

  float xf[2][8];

  auto pfX = [&](int kc){
    #pragma unroll
    for(int p = 0; p < 2; p++){
      const int idx = p * 256 + tid;
      const int kg = idx >> 6, n = idx & 63;
      const float* xp = xpb + (size_t)(kc + kg * 8) * N + n;
      #pragma unroll
      for(int j = 0; j < 8; j++) xf[p][j] = xp[(size_t)j * N];
    }
  };
  auto stX = [&](){
    #pragma unroll
    for(int p = 0; p < 2; p++){
      const int idx = p * 256 + tid;
      const int kg = idx >> 6, n = idx & 63;
      uint4 v;
      v.x = pack2(xf[p][0], xf[p][1]); v.y = pack2(xf[p][2], xf[p][3]);
      v.z = pack2(xf[p][4], xf[p][5]); v.w = pack2(xf[p][6], xf[p][7]);
      *(uint4*)&xlds[(kg * 64 + n) * 8] = v;
    }
  };
  auto stW = [&](int kc){
    #pragma unroll
    for(int q = 0; q < 10; q++){
      const int pidx = q * 256 + tid;        // 0..2559
      const int kg = pidx / 320;
      const int m  = pidx - kg * 320;
      uint4 v = *(const uint4*)(wbf + (size_t)m * 256 + kc + kg * 8);
      *(uint4*)&wlds[(kg * 320 + m) * 8] = v;
    }
  };
  auto mfmaC = [&](){
    #pragma unroll
    for(int ks = 0; ks < 4; ks++){
      const int kg = ks * 2 + lhi;
      bf16x8 bfr = *(const bf16x8*)&xlds[(kg * 64 + nwv + l31) * 8];
      #pragma unroll
      for(int t = 0; t < 5; t++){
        const int m0 = (mrow + 2 * t) * 32;
        bf16x8 af = *(const bf16x8*)&wlds[(kg * 320 + m0 + l31) * 8];
        acc[t] = __builtin_amdgcn_mfma_f32_32x32x16_bf16(af, bfr, acc[t], 0, 0, 0);
      }
    }
  };

  // prologue: stage chunk 0
  stW(0); pfX(0); stX();
  __syncthreads();
  // chunk 0
  pfX(64);
  mfmaC();
  __syncthreads();
  stW(64); stX();
  __syncthreads();
  // chunk 1
  pfX(128);
  mfmaC();
  __syncthreads();
  stW(128); stX();
  __syncthreads();
  // chunk 2
  pfX(192);
  mfmaC();
  __syncthreads();
  stW(192); stX();
  __syncthreads();
  // chunk 3
  mfmaC();

  // epilogue: C/D layout col=lane&31, row=(r&3)+8*(r>>2)+4*lhi
  const int n = n0 + nwv + l31;
  #pragma unroll
  for(int t = 0; t < 5; t++){
    const int mt = (mrow + 2 * t) * 32;
    #pragma unroll
    for(int r = 0; r < 16; r++){
      const int row = (r & 3) + 8 * (r >> 2) + 4 * lhi;
      const int o = mt + row;
      if(o >= O1) continue;
      const float v = acc[t][r] + sbias[o];
      if(o < 256)
        ctxb[((size_t)(b * 256 + o)) * N + n] = (ushort_t)f2bf(v);
      else
        gates[((size_t)(b * 4 + (o - 256))) * N + n] = v;
    }
  }
}

// ---------------- fused depthwise chain (R4/R6-proven bf16 LDS tiles) -------
// NOTE: row stride 72 shorts = 36 dwords == 4 (mod 32 banks) -> benign for
// b128 reads; do NOT change to fp32/72-float stride (8 mod 32 -> 16-way).
constexpr int SSTR = 72;

DEVFN void unpack16(const short* p, float* wnd){
  uint4 a = *(const uint4*)p;
  uint4 b = *(const uint4*)(p + 8);
  unsigned ua[8] = {a.x, a.y, a.z, a.w, b.x, b.y, b.z, b.w};
  #pragma unroll
  for(int d = 0; d < 8; d++){ wnd[2*d] = lo2f(ua[d]); wnd[2*d+1] = hi2f(ua[d]); }
}

template<int K>
DEVFN void dw_stage(const short* src, const float* __restrict__ fw, int c,
                    int h, int w0, float* val){
  constexpr int R = K / 2;
  float acc[8];
  #pragma unroll
  for(int i = 0; i < 8; i++) acc[i] = 0.f;
  #pragma unroll
  for(int ky = 0; ky < K; ky++){
    const int r = h + ky - R;
    if((unsigned)r < 64u){
      float wnd[16];
      unpack16(&src[r * SSTR + w0], wnd);       // covers cols [w0-4, w0+12)
      #pragma unroll
      for(int kx = 0; kx < K; kx++){
        const float wv = fw[c * K * K + ky * K + kx];   // uniform -> SGPR
        #pragma unroll
        for(int i = 0; i < 8; i++)
          acc[i] = fmaf(wnd[i + kx + 4 - R], wv, acc[i]);
      }
    }
  }
  #pragma unroll
  for(int i = 0; i < 8; i++) val[i] = gelu_fast(acc[i]);
}

DEVFN void store_row(short* dst, int h, int w0, const float* val){
  bf16x4 lo, hi;
  #pragma unroll
  for(int i = 0; i < 4; i++){ lo[i] = f2bf(val[i]); hi[i] = f2bf(val[i + 4]); }
  *(bf16x4*)&dst[h * SSTR + w0 + 4] = lo;
  *(bf16x4*)&dst[h * SSTR + w0 + 8] = hi;
}

__global__ __launch_bounds__(512, 8)
void k_dwchain(ushort_t* __restrict__ ctxb, const float* __restrict__ fw3,
               const float* __restrict__ fw5, const float* __restrict__ fw7,
               const float* __restrict__ gates){
  __shared__ __align__(16) short bufA[64 * SSTR];
  __shared__ __align__(16) short bufB[64 * SSTR];
  __shared__ float wred[8];
  const int tid = threadIdx.x;
  const int plane = blockIdx.x;
  const int b = plane >> 8;
  const int c = plane & 255;
  const int h  = tid >> 3;
  const int w0 = (tid & 7) * 8;
  const int nbase = h * 64 + w0;

  if(tid < 64){
    bf16x4 z = {0, 0, 0, 0};
    *(bf16x4*)&bufA[tid * SSTR] = z;  *(bf16x4*)&bufA[tid * SSTR + 68] = z;
    *(bf16x4*)&bufB[tid * SSTR] = z;  *(bf16x4*)&bufB[tid * SSTR + 68] = z;
  }
  {
    bf16x8 iv = *(const bf16x8*)((const short*)ctxb + (size_t)plane * N + tid * 8);
    bf16x4 lo, hi;
    #pragma unroll
    for(int j = 0; j < 4; j++){ lo[j] = iv[j]; hi[j] = iv[j + 4]; }
    *(bf16x4*)&bufA[h * SSTR + w0 + 4] = lo;
    *(bf16x4*)&bufA[h * SSTR + w0 + 8] = hi;
  }
  __syncthreads();

  float ctxp[8];
  #pragma unroll
  for(int i = 0; i < 8; i++) ctxp[i] = 0.f;
  float val[8];

  // stage 1: dw3 A->B
  dw_stage<3>(bufA, fw3, c, h, w0, val);
  {
    const float* gp = gates + ((size_t)(b * 4 + 0)) * N + nbase;
    float4 ga = *(const float4*)gp, gb = *(const float4*)(gp + 4);
    ctxp[0] = fmaf(val[0], ga.x, ctxp[0]); ctxp[1] = fmaf(val[1], ga.y, ctxp[1]);
    ctxp[2] = fmaf(val[2], ga.z, ctxp[2]); ctxp[3] = fmaf(val[3], ga.w, ctxp[3]);
    ctxp[4] = fmaf(val[4], gb.x, ctxp[4]); ctxp[5] = fmaf(val[5], gb.y, ctxp[5]);
    ctxp[6] = fmaf(val[6], gb.z, ctxp[6]); ctxp[7] = fmaf(val[7], gb.w, ctxp[7]);
    store_row(bufB, h, w0, val);
  }
  __syncthreads();

  // stage 2: dw5 B->A
  dw_stage<5>(bufB, fw5, c, h, w0, val);
  {
    const float* gp = gates + ((size_t)(b * 4 + 1)) * N + nbase;
    float4 ga = *(const float4*)gp, gb = *(const float4*)(gp + 4);
    ctxp[0] = fmaf(val[0], ga.x, ctxp[0]); ctxp[1] = fmaf(val[1], ga.y, ctxp[1]);
    ctxp[2] = fmaf(val[2], ga.z, ctxp[2]); ctxp[3] = fmaf(val[3], ga.w, ctxp[3]);
    ctxp[4] = fmaf(val[4], gb.x, ctxp[4]); ctxp[5] = fmaf(val[5], gb.y, ctxp[5]);
    ctxp[6] = fmaf(val[6], gb.z, ctxp[6]); ctxp[7] = fmaf(val[7], gb.w, ctxp[7]);
    store_row(bufA, h, w0, val);
  }
  __syncthreads();

  // stage 3: dw7 A->regs; plane mean of gelu output
  dw_stage<7>(bufA, fw7, c, h, w0, val);
  float lsum = 0.f;
  {
    const float* gp = gates + ((size_t)(b * 4 + 2)) * N + nbase;
    float4 ga = *(const float4*)gp, gb = *(const float4*)(gp + 4);
    ctxp[0] = fmaf(val[0], ga.x, ctxp[0]); ctxp[1] = fmaf(val[1], ga.y, ctxp[1]);
    ctxp[2] = fmaf(val[2], ga.z, ctxp[2]); ctxp[3] = fmaf(val[3], ga.w, ctxp[3]);
    ctxp[4] = fmaf(val[4], gb.x, ctxp[4]); ctxp[5] = fmaf(val[5], gb.y, ctxp[5]);
    ctxp[6] = fmaf(val[6], gb.z, ctxp[6]); ctxp[7] = fmaf(val[7], gb.w, ctxp[7]);
    #pragma unroll
    for(int i = 0; i < 8; i++) lsum += val[i];
  }
  #pragma unroll
  for(int off = 32; off > 0; off >>= 1) lsum += __shfl_xor(lsum, off, 64);
  if((tid & 63) == 0) wred[tid >> 6] = lsum;
  __syncthreads();
  float mean = 0.f;
  #pragma unroll
  for(int i = 0; i < 8; i++) mean += wred[i];
  mean *= (1.0f / 4096.0f);

  // ctx_all = ctxp + mean*g3 -> bf16, in place
  {
    const float* gp = gates + ((size_t)(b * 4 + 3)) * N + nbase;
    float4 ga = *(const float4*)gp, gb = *(const float4*)(gp + 4);
    bf16x8 ov;
    ov[0] = f2bf(fmaf(mean, ga.x, ctxp[0])); ov[1] = f2bf(fmaf(mean, ga.y, ctxp[1]));
    ov[2] = f2bf(fmaf(mean, ga.z, ctxp[2])); ov[3] = f2bf(fmaf(mean, ga.w, ctxp[3]));
    ov[4] = f2bf(fmaf(mean, gb.x, ctxp[4])); ov[5] = f2bf(fmaf(mean, gb.y, ctxp[5]));
    ov[6] = f2bf(fmaf(mean, gb.z, ctxp[6])); ov[7] = f2bf(fmaf(mean, gb.w, ctxp[7]));
    *(bf16x8*)((short*)ctxb + (size_t)plane * N + nbase) = ov;
  }
}

// ---------------- logits[b,n] = sum_c kw[c]*ctxall[b,c,n] + kb (bf16 read) ----
__global__ __launch_bounds__(256)
void k_logits(const ushort_t* __restrict__ P, const float* __restrict__ key_w,
              const float* __restrict__ key_b, float* __restrict__ logits){
  __shared__ float kw[256];
  __shared__ float part[512];
  int tid = threadIdx.x;
  kw[tid] = key_w[tid];
  __syncthreads();
  int b  = blockIdx.x >> 5;
  int n0 = (blockIdx.x & 31) * 128;
  int cpart = tid >> 6, pxp = tid & 63;
  const ushort_t* pp = P + ((size_t)(b * 256 + cpart * 64)) * N + n0 + pxp * 2;
  float a0 = 0.f, a1 = 0.f;
  #pragma unroll 8
  for(int c = 0; c < 64; c++){
    unsigned u = *(const unsigned*)(pp + (size_t)c * N);
    float kwv = kw[cpart * 64 + c];
    a0 = fmaf(lo2f(u), kwv, a0);
    a1 = fmaf(hi2f(u), kwv, a1);
  }
  part[cpart * 128 + pxp * 2]     = a0;
  part[cpart * 128 + pxp * 2 + 1] = a1;
  __syncthreads();
  if(tid < 128){
    float l = part[tid] + part[128 + tid] + part[256 + tid] + part[384 + tid];
    logits[b * N + n0 + tid] = l + key_b[0];
  }
}

// ---------------- softmax over N per batch (1024 thr, shfl reduce) ----------
__global__ __launch_bounds__(1024)
void k_softmax(float* __restrict__ kbuf){
  __shared__ float wred[16];
  int b = blockIdx.x, tid = threadIdx.x;
  const int wave = tid >> 6, lane = tid & 63;
  float v[4];
  float m = -1e30f;
  #pragma unroll
  for(int i = 0; i < 4; i++){
    v[i] = kbuf[b * N + tid + i * 1024];
    m = fmaxf(m, v[i]);
  }
  #pragma unroll
  for(int off = 32; off > 0; off >>= 1) m = fmaxf(m, __shfl_xor(m, off, 64));
  if(lane == 0) wred[wave] = m;
  __syncthreads();
  float mm = -1e30f;
  #pragma unroll
  for(int i = 0; i < 16; i++) mm = fmaxf(mm, wred[i]);
  __syncthreads();
  float s = 0.f;
  #pragma unroll
  for(int i = 0; i < 4; i++){ v[i] = __expf(v[i] - mm); s += v[i]; }
  #pragma unroll
  for(int off = 32; off > 0; off >>= 1) s += __shfl_xor(s, off, 64);
  if(lane == 0) wred[wave] = s;
  __syncthreads();
  float tot = 0.f;
  #pragma unroll
  for(int i = 0; i < 16; i++) tot += wred[i];
  float inv = 1.0f / tot;
  #pragma unroll
  for(int i = 0; i < 4; i++)
    kbuf[b * N + tid + i * 1024] = v[i] * inv;
}

// ---------------- qk[b,c] = sum_n ctxall[b,c,n]*k[b,n] (bf16 read) ----------
__global__ __launch_bounds__(256)
void k_qk(const ushort_t* __restrict__ P, const float* __restrict__ kbuf,
          float* __restrict__ qk){
  __shared__ float red[256];
  int plane = blockIdx.x, tid = threadIdx.x;
  int b = plane >> 8;
  const unsigned* pp = (const unsigned*)(P + (size_t)plane * N);
  const float2* kp = (const float2*)(kbuf + b * N);
  float acc = 0.f;
  #pragma unroll
  for(int i = 0; i < 8; i++){
    int idx = tid + i * 256;
    unsigned u = pp[idx];
    float2 kk = kp[idx];
    acc = fmaf(lo2f(u), kk.x, acc);
    acc = fmaf(hi2f(u), kk.y, acc);
  }
  red[tid] = acc; __syncthreads();
  for(int s = 128; s > 0; s >>= 1){
    if(tid < s) red[tid] += red[tid + s];
    __syncthreads();
  }
  if(tid == 0) qk[plane] = red[0];
}

// ---------------- v pipeline per batch ----------
__global__ __launch_bounds__(256)
void k_v(const float* __restrict__ qk, const float* __restrict__ v1w,
         const float* __restrict__ v1b, const float* __restrict__ lnw,
         const float* __restrict__ lnb, const float* __restrict__ v2w,
         const float* __restrict__ v2b, float* __restrict__ vout){
  int b = blockIdx.x, tid = threadIdx.x;
  __shared__ float qs[256];
  __shared__ float part[256];
  __shared__ float v1s[16];
  __shared__ float vr[16];
  __shared__ float stats[2];
  qs[tid] = qk[b * 256 + tid];
  __syncthreads();
  int oc = tid >> 4, ln = tid & 15;
  float p = 0.f;
  #pragma unroll
  for(int j = 0; j < 16; j++){
    int cc = ln + j * 16;
    p = fmaf(v1w[oc * 256 + cc], qs[cc], p);
  }
  part[tid] = p;
  __syncthreads();
  if(tid < 16){
    float s = v1b[tid];
    for(int j = 0; j < 16; j++) s += part[tid * 16 + j];
    v1s[tid] = s;
  }
  __syncthreads();
  if(tid == 0){
    float mu = 0.f;
    for(int i = 0; i < 16; i++) mu += v1s[i];
    mu *= (1.f / 16.f);
    float var = 0.f;
    for(int i = 0; i < 16; i++){ float d = v1s[i] - mu; var += d * d; }
    var *= (1.f / 16.f);
    stats[0] = mu; stats[1] = rsqrtf(var + 1e-5f);
  }
  __syncthreads();
  if(tid < 16){
    float vv = (v1s[tid] - stats[0]) * stats[1] * lnw[tid] + lnb[tid];
    vr[tid] = fmaxf(vv, 0.f);
  }
  __syncthreads();
  float o = v2b[tid];
  #pragma unroll
  for(int j = 0; j < 16; j++) o = fmaf(v2w[tid * 16 + j], vr[j], o);
  vout[b * 256 + tid] = o;
}

// ---------------- out = f32(ctxall_bf16) + vout (pure write) ----------
__global__ __launch_bounds__(256)
void k_final(float* __restrict__ out, const ushort_t* __restrict__ ctxb,
             const float* __restrict__ vout){
  int idx8 = blockIdx.x * 256 + threadIdx.x;
  int plane = idx8 >> 9;
  int off = (idx8 & 511) * 8;
  bf16x8 v = *(const bf16x8*)((const short*)ctxb + (size_t)plane * N + off);
  float vv = vout[plane];
  float4 o0, o1;
  o0.x = bf2f((ushort_t)v[0]) + vv; o0.y = bf2f((ushort_t)v[1]) + vv;
  o0.z = bf2f((ushort_t)v[2]) + vv; o0.w = bf2f((ushort_t)v[3]) + vv;
  o1.x = bf2f((ushort_t)v[4]) + vv; o1.y = bf2f((ushort_t)v[5]) + vv;
  o1.z = bf2f((ushort_t)v[6]) + vv; o1.w = bf2f((ushort_t)v[7]) + vv;
  float* op = out + (size_t)plane * N + off;
  *(float4*)op = o0;
  *(float4*)(op + 4) = o1;
}

extern "C" void kernel_launch(void* const* d_in, const int* in_sizes, int n_in,
                              void* d_out, int out_size, void* d_ws, size_t ws_size,
                              hipStream_t stream){
  const float* x      = (const float*)d_in[0];
  const float* conv_w = (const float*)d_in[1];
  const float* conv_b = (const float*)d_in[2];
  const float* fw3    = (const float*)d_in[3];
  const float* fw5    = (const float*)d_in[4];
  const float* fw7    = (const float*)d_in[5];
  const float* key_w  = (const float*)d_in[6];
  const float* key_b  = (const float*)d_in[7];
  const float* v1_w   = (const float*)d_in[8];
  const float* v1_b   = (const float*)d_in[9];
  const float* ln_w   = (const float*)d_in[10];
  const float* ln_b   = (const float*)d_in[11];
  const float* v2_w   = (const float*)d_in[12];
  const float* v2_b   = (const float*)d_in[13];
  float* out = (float*)d_out;

  const size_t PL = (size_t)B * C * N;     // 16,777,216 elements
  char* p = (char*)d_ws;
  ushort_t* ctxb = (ushort_t*)p;  p += PL * sizeof(ushort_t);          // 32 MB
  float* gates   = (float*)p;     p += (size_t)B * 4 * N * sizeof(float);
  float* kbuf    = (float*)p;     p += (size_t)B * N * sizeof(float);
  float* qkb     = (float*)p;     p += (size_t)B * C * sizeof(float);
  float* vout    = (float*)p;     p += (size_t)B * C * sizeof(float);
  ushort_t* wbf  = (ushort_t*)p;  // 320*256 bf16

  // 0. pre-convert W to zero-padded bf16 [320][256]
  k_wbf<<<320, 256, 0, stream>>>(conv_w, wbf);
  // 1. conv1x1 via bf16 MFMA, single pass over x
  k_conv1_mfma<<<1024, 256, 0, stream>>>(x, wbf, conv_b, ctxb, gates);
  // 2. fused dw3/dw5/dw7 chain -> ctxb overwritten with bf16 ctx_all
  k_dwchain<<<B * C, 512, 0, stream>>>(ctxb, fw3, fw5, fw7, gates);
  // 3. logits (reads bf16 ctx_all)
  k_logits<<<512, 256, 0, stream>>>(ctxb, key_w, key_b, kbuf);
  // 4. softmax
  k_softmax<<<B, 1024, 0, stream>>>(kbuf);
  // 5. qk (reads bf16 ctx_all)
  k_qk<<<B * C, 256, 0, stream>>>(ctxb, kbuf, qkb);
  // 6. v pipeline
  k_v<<<B, 256, 0, stream>>>(qkb, v1_w, v1_b, ln_w, ln_b, v2_w, v2_b, vout);
  // 7. final: out = f32(ctx_all) + v broadcast (pure write)
  k_final<<<8192, 256, 0, stream>>>(out, ctxb, vout);
}